// Round 4
// baseline (466.775 us; speedup 1.0000x reference)
//
#include <hip/hip_runtime.h>

// FrozenHopfield: obs-mean -> random projection -> cosine-sim attention over
// vocab embeddings -> softmax(beta*sims) @ word_embs.
//
// B=256, C=3, HW=7056, HID=768, VOCAB=50257. Two big GEMMs in bf16 MFMA
// 16x16x32, fp32 accumulate. Logits bounded in [-8,8] so softmax needs no
// max subtraction: E=exp(logit), state=(E@W)/rowsum(E).
//
// R2: packed stores only (scattered shorts = 37x write amplification).
// R3: partial-coverage LDS store phases are silent poison; annotate coverage.
// R4: k_qgemm K-split 17 ways (was latency-bound at 48 blocks).
// R5/R6: two k_wprep micro-fixes (bank conflicts, load reorder) = ZERO delta;
// the cost was structural.
// R7 (win, 449->415): WbT eliminated; gemm2 transposes its A-tile during LDS
// staging from row-major Wb. k_wprep is now a pure stream (read W -> bf16 Wb +
// inv_en). Top-5 dispatches now the harness's own 88us workspace fill.
// R8: gemm2 b-blocks merged (128h x 256b tile, acc 4x8): Wb read ONCE (77 MB,
// was 2x), each staged A-byte feeds 2x MFMA. SPLITS 32->44 (264 blocks) keeps
// every CU fed; k_reduce follows.

#define VOCAB 50257
#define VPAD  50304   // 393*128
#define HID   768
#define BATCH 256
#define IN    7056
#define INPAD 7072    // 221*32 = 17*416
#define NPAIR (INPAD / 2)   // 3536
#define SPLITS 44
#define CHUNK 1152    // gemm2 k-elems per split (36 k-steps; last split 24)
#define QSPLITS 17
#define QCHUNK 416    // 13 iters of 32

typedef __attribute__((ext_vector_type(8))) __bf16 bf16x8;
typedef __attribute__((ext_vector_type(4))) float f32x4;

__device__ inline unsigned short f2bf(float f) {
  union { float f; unsigned u; } v; v.f = f;
  unsigned r = v.u + 0x7fffu + ((v.u >> 16) & 1u);   // RNE
  return (unsigned short)(r >> 16);
}
__device__ inline unsigned pack2(float lo, float hi) {
  return (unsigned)f2bf(lo) | ((unsigned)f2bf(hi) << 16);
}

// ---------------- W prep: Wb (bf16) + inv_en in one streaming pass ----------
// Pure stream: wave w owns rows w*8..w*8+7 of a 32-row block; per row 64 lanes
// read 3 contiguous 1KB float4 chunks, convert, store Wb uint2 (coalesced
// 512B/wave), 3 xor-shfls -> ssb[32][8] partials, tiny finish pass -> inv_en.
__global__ __launch_bounds__(256, 3) void k_wprep(const float* __restrict__ W,
                                                  unsigned* __restrict__ Wb,    // [VPAD][384] uint pairs
                                                  float* __restrict__ inv_en) {
  __shared__ float ssb[32][8];   // per-row 8 partial sums of squares
  const int t = threadIdx.x;
  const int lane = t & 63, wave = t >> 6;
  const int v0 = blockIdx.x * 32;

  // bulk-issue all 24 loads (rows clamped to VOCAB-1: uniform, branch-free)
  float4 xv[8][3];
#pragma unroll
  for (int rr = 0; rr < 8; rr++) {
    const int v = v0 + wave * 8 + rr;
    const int vc = (v < VOCAB) ? v : (VOCAB - 1);
    const float* wrow = &W[(size_t)vc * HID + lane * 4];
#pragma unroll
    for (int c = 0; c < 3; c++)
      xv[rr][c] = *(const float4*)(wrow + c * 256);
  }
  __builtin_amdgcn_sched_barrier(0);   // pin: all loads issued before any store
#pragma unroll
  for (int rr = 0; rr < 8; rr++) {
    const int row = wave * 8 + rr;
    const int v = v0 + row;
    const bool valid = (v < VOCAB);
    unsigned* wbrow = &Wb[(size_t)v * (HID / 2) + lane * 2];
    float ss = 0.f;
#pragma unroll
    for (int c = 0; c < 3; c++) {
      float4 x = xv[rr][c];
      if (!valid) x = (float4){0.f, 0.f, 0.f, 0.f};
      *(uint2*)&wbrow[c * 128] = (uint2){pack2(x.x, x.y), pack2(x.z, x.w)};
      ss += x.x * x.x + x.y * x.y + x.z * x.z + x.w * x.w;
    }
    // 64 lane-partials -> 8 (xor 1,2,4 within 8-lane groups)
    ss += __shfl_xor(ss, 1, 64);
    ss += __shfl_xor(ss, 2, 64);
    ss += __shfl_xor(ss, 4, 64);
    if ((lane & 7) == 0) ssb[row][lane >> 3] = ss;
  }
  __syncthreads();
  // finish inv_en: 256 threads = 32 rows x 8 partials (identity map, no conflicts)
  {
    const int row = t >> 3, j = t & 7;
    float s = ssb[row][j];
    s += __shfl_xor(s, 1, 64);
    s += __shfl_xor(s, 2, 64);
    s += __shfl_xor(s, 4, 64);
    if (j == 0) {
      const int v = v0 + row;
      inv_en[v] = (v < VOCAB) ? (1.f / sqrtf(s)) : 0.f;
    }
  }
}

// obsb[b][i] = bf16(mean_c obs[b][c][i]), zero pad cols; packed uint stores
__global__ __launch_bounds__(256) void k_obs(const float* __restrict__ obs,
                                             unsigned* __restrict__ obsb) {
  int b = blockIdx.x, t = threadIdx.x;
  const size_t base = (size_t)b * 3 * IN;
  for (int p = t; p < NPAIR; p += 256) {
    float x = 0.f, y = 0.f;
    if (2 * p < IN) {   // IN even: pair never straddles the boundary
      float2 a0 = *(const float2*)&obs[base + 2 * p];
      float2 a1 = *(const float2*)&obs[base + IN + 2 * p];
      float2 a2 = *(const float2*)&obs[base + 2 * IN + 2 * p];
      x = (a0.x + a1.x + a2.x) * (1.f / 3.f);
      y = (a0.y + a1.y + a2.y) * (1.f / 3.f);
    }
    obsb[b * NPAIR + p] = pack2(x, y);
  }
}

__global__ __launch_bounds__(256) void k_proj(const float* __restrict__ proj,
                                              unsigned* __restrict__ projb) {
  int h = blockIdx.x, t = threadIdx.x;
  for (int p = t; p < NPAIR; p += 256) {
    float x = 0.f, y = 0.f;
    if (2 * p < IN) {
      float2 xy = *(const float2*)&proj[(size_t)h * IN + 2 * p];
      x = xy.x; y = xy.y;
    }
    projb[h * NPAIR + p] = pack2(x, y);
  }
}

// ---------------- q projection GEMM (K-split): qp[s] = partial obs @ proj^T ----

__global__ __launch_bounds__(256) void k_qgemm(const unsigned short* __restrict__ A,  // obsb [256][INPAD]
                                               const unsigned short* __restrict__ Bm, // projb [768][INPAD]
                                               float* __restrict__ qp) {              // [QSPLITS][256][768]
  __shared__ unsigned short As[64][32];
  __shared__ unsigned short Bs[64][32];
  const int t = threadIdx.x;
  const int lane = t & 63, wave = t >> 6;
  const int wm = wave >> 1, wn = wave & 1;
  const int quad = lane >> 4, lo = lane & 15;
  const int m0 = blockIdx.y * 64, n0 = blockIdx.x * 64;
  const int split = blockIdx.z;
  const int kbeg = split * QCHUNK, kend = kbeg + QCHUNK;
  const int ar = t >> 2, ac = (t & 3) * 8;
  f32x4 acc[2][2];
  for (int i = 0; i < 2; i++)
    for (int j = 0; j < 2; j++) acc[i][j] = (f32x4){0.f, 0.f, 0.f, 0.f};
  const unsigned short* aptr = &A[(m0 + ar) * INPAD + ac];
  const unsigned short* bptr = &Bm[(n0 + ar) * INPAD + ac];
  for (int k0 = kbeg; k0 < kend; k0 += 32) {
    uint4 av = *(const uint4*)(aptr + k0);
    uint4 bv = *(const uint4*)(bptr + k0);
    __syncthreads();
    *(uint4*)&As[ar][ac] = av;
    *(uint4*)&Bs[ar][ac] = bv;
    __syncthreads();
    bf16x8 af[2], bfr[2];
    for (int i = 0; i < 2; i++) {
      af[i]  = *(const bf16x8*)&As[wm * 32 + i * 16 + lo][quad * 8];
      bfr[i] = *(const bf16x8*)&Bs[wn * 32 + i * 16 + lo][quad * 8];
    }
    for (int mi = 0; mi < 2; mi++)
      for (int ni = 0; ni < 2; ni++)
        acc[mi][ni] = __builtin_amdgcn_mfma_f32_16x16x32_bf16(af[mi], bfr[ni], acc[mi][ni], 0, 0, 0);
  }
  float* outp = qp + (size_t)split * BATCH * HID;
  for (int mi = 0; mi < 2; mi++)
    for (int ni = 0; ni < 2; ni++)
      for (int r = 0; r < 4; r++) {
        int row = m0 + wm * 32 + mi * 16 + quad * 4 + r;   // b
        int col = n0 + wn * 32 + ni * 16 + lo;             // h
        outp[row * HID + col] = acc[mi][ni][r];            // 4B/lane, 16-lane contig
      }
}

// qhat[b][h] = bf16(sum_s qp * beta/||q_b||); packed uint stores; zero l
__global__ __launch_bounds__(384) void k_qhat(const float* __restrict__ qp,
                                              const int* __restrict__ beta,
                                              unsigned* __restrict__ qhat,
                                              float* __restrict__ l) {
  int b = blockIdx.x, t = threadIdx.x;   // 384 threads: pair t = cols 2t,2t+1
  float x = 0.f, y = 0.f;
  for (int s = 0; s < QSPLITS; s++) {
    float2 p = *(const float2*)&qp[(size_t)s * BATCH * HID + b * HID + 2 * t];
    x += p.x; y += p.y;
  }
  float ss = x * x + y * y;
  for (int m = 1; m < 64; m <<= 1) ss += __shfl_xor(ss, m, 64);
  __shared__ float sacc[6];
  if ((t & 63) == 0) sacc[t >> 6] = ss;
  __syncthreads();
  float tot = sacc[0] + sacc[1] + sacc[2] + sacc[3] + sacc[4] + sacc[5];
  // ref denom is (qn*en + 1e-8); qn*en ~ 1.3e3 so eps is rel ~7e-12: folded out.
  float scale = (float)beta[0] / sqrtf(tot);
  qhat[b * (HID / 2) + t] = pack2(x * scale, y * scale);
  if (t == 0) l[b] = 0.f;
}

// ---------------- GEMM1: E = exp((qhat @ Wb^T) * inv_en), rowsums into l ----
// grid (2 m-blocks, 393 n-blocks): adjacent blocks share the Wb stripe -> L2 hit.

__global__ __launch_bounds__(256) void k_gemm1(const unsigned short* __restrict__ A,   // qhat [256][768]
                                               const unsigned short* __restrict__ Bm,  // Wb [VPAD][768]
                                               const float* __restrict__ inv_en,
                                               unsigned short* __restrict__ E,         // [256][VPAD]
                                               float* __restrict__ l) {
  __shared__ unsigned short As[128][32];
  __shared__ unsigned short Bs[128][32];
  __shared__ unsigned short Et[128][128];   // staged output tile (32 KB)
  __shared__ float rowsum[128];
  const int t = threadIdx.x;
  const int lane = t & 63, wave = t >> 6;
  const int wm = wave >> 1, wn = wave & 1;
  const int quad = lane >> 4, lo = lane & 15;
  const int m0 = blockIdx.x * 128, n0 = blockIdx.y * 128;
  const int ar = t >> 2, ac = (t & 3) * 8;
  if (t < 128) rowsum[t] = 0.f;
  f32x4 acc[4][4];
  for (int i = 0; i < 4; i++)
    for (int j = 0; j < 4; j++) acc[i][j] = (f32x4){0.f, 0.f, 0.f, 0.f};
  const unsigned short* aptr  = &A[(m0 + ar) * HID + ac];
  const unsigned short* aptr2 = &A[(m0 + ar + 64) * HID + ac];
  const unsigned short* bptr  = &Bm[(size_t)(n0 + ar) * HID + ac];
  const unsigned short* bptr2 = &Bm[(size_t)(n0 + ar + 64) * HID + ac];
  for (int k0 = 0; k0 < HID; k0 += 32) {
    uint4 av0 = *(const uint4*)(aptr + k0);
    uint4 av1 = *(const uint4*)(aptr2 + k0);
    uint4 bv0 = *(const uint4*)(bptr + k0);
    uint4 bv1 = *(const uint4*)(bptr2 + k0);
    __syncthreads();
    *(uint4*)&As[ar][ac]      = av0;
    *(uint4*)&As[ar + 64][ac] = av1;
    *(uint4*)&Bs[ar][ac]      = bv0;
    *(uint4*)&Bs[ar + 64][ac] = bv1;
    __syncthreads();
    bf16x8 af[4], bfr[4];
    for (int i = 0; i < 4; i++) {
      af[i]  = *(const bf16x8*)&As[wm * 64 + i * 16 + lo][quad * 8];
      bfr[i] = *(const bf16x8*)&Bs[wn * 64 + i * 16 + lo][quad * 8];
    }
    for (int mi = 0; mi < 4; mi++)
      for (int ni = 0; ni < 4; ni++)
        acc[mi][ni] = __builtin_amdgcn_mfma_f32_16x16x32_bf16(af[mi], bfr[ni], acc[mi][ni], 0, 0, 0);
  }
  // epilogue: E = exp(acc * inv_en) into LDS tile + rowsum reduce
  for (int mi = 0; mi < 4; mi++)
    for (int ni = 0; ni < 4; ni++) {
      int cl = wn * 64 + ni * 16 + lo;
      int vg = n0 + cl;
      bool valid = (vg < VOCAB);
      float ie = inv_en[vg];
      for (int r = 0; r < 4; r++) {
        int row = wm * 64 + mi * 16 + quad * 4 + r;
        float e = valid ? __expf(acc[mi][ni][r] * ie) : 0.f;   // logits in [-8,8]
        Et[row][cl] = f2bf(e);
        float s = e;
        s += __shfl_xor(s, 1, 64);
        s += __shfl_xor(s, 2, 64);
        s += __shfl_xor(s, 4, 64);
        s += __shfl_xor(s, 8, 64);
        if (lo == 0) atomicAdd(&rowsum[row], s);
      }
    }
  __syncthreads();
  // cooperative full-line writes: 128 rows x 256B: 2048 uint4 = 8 passes x 256
  for (int i = 0; i < 8; i++) {
    int idx = t + i * 256;
    int row = idx >> 4, j = idx & 15;
    *(uint4*)&E[(size_t)(m0 + row) * VPAD + n0 + j * 8] = *(const uint4*)&Et[row][j * 8];
  }
  if (t < 128) atomicAdd(&l[m0 + t], rowsum[t]);
}

// ---------------- GEMM2 (K-split): Pp[s][h][b] = partial sum_v Wb[v][h]*E[b][v] ----
// Tile 128h x 256b (all of batch in one block): Wb read ONCE across the grid.
// A-tile transposed during staging from row-major Wb: thread t reads Wb row
// v=t>>3, h-chunks (t&7),(t&7)+8 as uint4 (coalesced 128B/row/wave), writes 16
// transposed ds_write_u16 into As[128][34] (pitch 17 dwords: write banks
// ~4-way, hidden under MFMA; frag reads 4xb32 ~2-way). B-tile: 256 rows of E,
// 4 uint4/thread. acc 4x8 f32x4 = 128 VGPR; ~25KB LDS.

__global__ __launch_bounds__(256) void k_gemm2(const unsigned short* __restrict__ Wb,  // [VPAD][768]
                                               const unsigned short* __restrict__ Bm,  // E [256][VPAD]
                                               float* __restrict__ Pp) {
  __shared__ unsigned short As[128][34];   // [m=h][k=v], padded pitch
  __shared__ unsigned short Bs[256][32];   // [n=b][k=v]
  const int t = threadIdx.x;
  const int lane = t & 63, wave = t >> 6;
  const int wm = wave >> 1, wn = wave & 1;
  const int quad = lane >> 4, lo = lane & 15;
  const int m0 = blockIdx.x * 128;          // m = h; n covers all 256 b
  const int split = blockIdx.y;
  const int kbeg = split * CHUNK;
  const int kend = (kbeg + CHUNK < VPAD) ? kbeg + CHUNK : VPAD;
  const int sv = t >> 3, shc = t & 7;      // A-staging: Wb row sv, h-chunks shc/shc+8
  const int br = t >> 2, bc = (t & 3) * 8; // B-staging: E rows br+{0,64,128,192}
  f32x4 acc[4][8];
  for (int i = 0; i < 4; i++)
    for (int j = 0; j < 8; j++) acc[i][j] = (f32x4){0.f, 0.f, 0.f, 0.f};
  const unsigned short* bptr0 = &Bm[(size_t)(br)       * VPAD + bc];
  const unsigned short* bptr1 = &Bm[(size_t)(br + 64)  * VPAD + bc];
  const unsigned short* bptr2 = &Bm[(size_t)(br + 128) * VPAD + bc];
  const unsigned short* bptr3 = &Bm[(size_t)(br + 192) * VPAD + bc];
  for (int k0 = kbeg; k0 < kend; k0 += 32) {
    uint4 a0  = *(const uint4*)&Wb[(size_t)(k0 + sv) * HID + m0 + shc * 8];
    uint4 a1  = *(const uint4*)&Wb[(size_t)(k0 + sv) * HID + m0 + (shc + 8) * 8];
    uint4 bv0 = *(const uint4*)(bptr0 + k0);
    uint4 bv1 = *(const uint4*)(bptr1 + k0);
    uint4 bv2 = *(const uint4*)(bptr2 + k0);
    uint4 bv3 = *(const uint4*)(bptr3 + k0);
    __syncthreads();
    {
      const unsigned short* e0 = (const unsigned short*)&a0;
      const unsigned short* e1 = (const unsigned short*)&a1;
#pragma unroll
      for (int j = 0; j < 8; j++) {
        As[shc * 8 + j][sv]       = e0[j];   // coverage: m 0..63 x v 0..31
        As[(shc + 8) * 8 + j][sv] = e1[j];   // coverage: m 64..127 x v 0..31
      }
    }
    *(uint4*)&Bs[br][bc]       = bv0;        // coverage: n 0..255 x k 0..31
    *(uint4*)&Bs[br + 64][bc]  = bv1;
    *(uint4*)&Bs[br + 128][bc] = bv2;
    *(uint4*)&Bs[br + 192][bc] = bv3;
    __syncthreads();
    bf16x8 af[4], bfr[8];
#pragma unroll
    for (int i = 0; i < 4; i++) {
      const unsigned* rp = (const unsigned*)&As[wm * 64 + i * 16 + lo][quad * 8];
      uint4 u; u.x = rp[0]; u.y = rp[1]; u.z = rp[2]; u.w = rp[3];   // 4x b32
      af[i] = *(const bf16x8*)&u;
    }
#pragma unroll
    for (int i = 0; i < 8; i++)
      bfr[i] = *(const bf16x8*)&Bs[wn * 128 + i * 16 + lo][quad * 8];
    for (int mi = 0; mi < 4; mi++)
      for (int ni = 0; ni < 8; ni++)
        acc[mi][ni] = __builtin_amdgcn_mfma_f32_16x16x32_bf16(af[mi], bfr[ni], acc[mi][ni], 0, 0, 0);
  }
  float* outp = Pp + (size_t)split * HID * BATCH;
  for (int mi = 0; mi < 4; mi++)
    for (int ni = 0; ni < 8; ni++)
      for (int r = 0; r < 4; r++) {
        int h = m0 + wm * 64 + mi * 16 + quad * 4 + r;
        int b = wn * 128 + ni * 16 + lo;
        outp[h * BATCH + b] = acc[mi][ni][r];   // 4B/lane, 16-lane contig
      }
}

// out[b][h] = (sum_s Pp[s][h][b]) / l[b]
__global__ __launch_bounds__(256) void k_reduce(const float* __restrict__ Pp,
                                                const float* __restrict__ l,
                                                float* __restrict__ out) {
  int idx = blockIdx.x * 256 + threadIdx.x;   // h*256 + b
  int h = idx >> 8, b = idx & 255;
  float s = 0.f;
  for (int i = 0; i < SPLITS; i++) s += Pp[(size_t)i * (HID * BATCH) + idx];
  out[b * HID + h] = s / l[b];
}

// ---------------- launch ----------------

extern "C" void kernel_launch(void* const* d_in, const int* in_sizes, int n_in,
                              void* d_out, int out_size, void* d_ws, size_t ws_size,
                              hipStream_t stream) {
  const float* obs  = (const float*)d_in[0];   // [256,3,84,84]
  const float* W    = (const float*)d_in[1];   // [50257,768]
  const float* proj = (const float*)d_in[2];   // [768,7056]
  const int* beta   = (const int*)d_in[3];     // scalar int
  float* out = (float*)d_out;                  // [256,768] f32

  char* ws = (char*)d_ws;
  size_t off = 0;
  auto alloc = [&](size_t bytes) -> void* {
    void* p = ws + off;
    off = (off + bytes + 255) & ~(size_t)255;
    return p;
  };
  unsigned short* Wb    = (unsigned short*)alloc((size_t)VPAD * HID * 2);   // 77.3 MB
  float* inv_en         = (float*)alloc((size_t)VPAD * 4);
  unsigned short* obsb  = (unsigned short*)alloc((size_t)BATCH * INPAD * 2);
  unsigned short* projb = (unsigned short*)alloc((size_t)HID * INPAD * 2);
  unsigned short* qhat  = (unsigned short*)alloc((size_t)BATCH * HID * 2);
  float* l              = (float*)alloc((size_t)BATCH * 4);
  unsigned short* E     = (unsigned short*)alloc((size_t)BATCH * VPAD * 2);  // 25.8 MB
  float* Pp             = (float*)alloc((size_t)SPLITS * BATCH * HID * 4);   // 34.6 MB
  float* qp             = Pp;   // alias: qp (13.4 MB) dead before gemm2 writes Pp
  (void)ws_size; (void)in_sizes; (void)n_in; (void)out_size;                 // ~139 MB total

  k_wprep<<<dim3(VPAD / 32), dim3(256), 0, stream>>>(W, (unsigned*)Wb, inv_en);
  k_obs  <<<dim3(BATCH), dim3(256), 0, stream>>>(obs, (unsigned*)obsb);
  k_proj <<<dim3(HID), dim3(256), 0, stream>>>(proj, (unsigned*)projb);
  k_qgemm<<<dim3(HID / 64, BATCH / 64, QSPLITS), dim3(256), 0, stream>>>(obsb, projb, qp);
  k_qhat <<<dim3(BATCH), dim3(384), 0, stream>>>(qp, beta, (unsigned*)qhat, l);
  k_gemm1<<<dim3(BATCH / 128, VPAD / 128), dim3(256), 0, stream>>>(qhat, Wb, inv_en, E, l);
  k_gemm2<<<dim3(HID / 128, SPLITS), dim3(256), 0, stream>>>(Wb, E, Pp);
  k_reduce<<<dim3(BATCH * HID / 256), dim3(256), 0, stream>>>(Pp, l, out);
}

// Round 5
// 406.221 us; speedup vs baseline: 1.1491x; 1.1491x over previous
//
#include <hip/hip_runtime.h>

// FrozenHopfield: obs-mean -> random projection -> cosine-sim attention over
// vocab embeddings -> softmax(beta*sims) @ word_embs.
//
// B=256, C=3, HW=7056, HID=768, VOCAB=50257. Two big GEMMs in bf16 MFMA
// 16x16x32, fp32 accumulate. Logits bounded in [-8,8] so softmax needs no
// max subtraction: E=exp(logit), state=(E@W)/rowsum(E).
//
// R2: packed stores only (scattered shorts = 37x write amplification).
// R3: partial-coverage LDS store phases are silent poison; annotate coverage.
// R4: k_qgemm K-split 17 ways (was latency-bound at 48 blocks).
// R5/R6: k_wprep micro-fixes = zero delta; cost was structural.
// R7 (win, 449->415): WbT eliminated; gemm2 transposes its A-tile during LDS
// staging from row-major Wb. k_wprep is a pure stream.
// R8 (regression, 415->467): merging gemm2's b-blocks (264 blocks) dropped
// occupancy to 1 block/CU (6%!) -> latency-serialized k-loop at 1.4 TB/s.
// Traffic was already L3-absorbed (FETCH 113MB ~= floor); concurrency was the
// constraint, not bytes. Reverted to the 3D grid.
// R9: register-prefetch pipeline in gemm1+gemm2 k-loops (T3-minimal): next
// k-step's 4 global loads issue right after staging, so their latency hides
// under ds_read+MFMA+barrier instead of stalling cold at the vmcnt(0) before
// the next ds_write.

#define VOCAB 50257
#define VPAD  50304   // 393*128
#define HID   768
#define BATCH 256
#define IN    7056
#define INPAD 7072    // 221*32 = 17*416
#define NPAIR (INPAD / 2)   // 3536
#define SPLITS 32
#define CHUNK 1600    // gemm2 k-elems per split (1600*32 = 51200 >= VPAD)
#define QSPLITS 17
#define QCHUNK 416    // 13 iters of 32

typedef __attribute__((ext_vector_type(8))) __bf16 bf16x8;
typedef __attribute__((ext_vector_type(4))) float f32x4;

__device__ inline unsigned short f2bf(float f) {
  union { float f; unsigned u; } v; v.f = f;
  unsigned r = v.u + 0x7fffu + ((v.u >> 16) & 1u);   // RNE
  return (unsigned short)(r >> 16);
}
__device__ inline unsigned pack2(float lo, float hi) {
  return (unsigned)f2bf(lo) | ((unsigned)f2bf(hi) << 16);
}

// ---------------- W prep: Wb (bf16) + inv_en in one streaming pass ----------
// Pure stream: wave w owns rows w*8..w*8+7 of a 32-row block; per row 64 lanes
// read 3 contiguous 1KB float4 chunks, convert, store Wb uint2 (coalesced
// 512B/wave), 3 xor-shfls -> ssb[32][8] partials, tiny finish pass -> inv_en.
__global__ __launch_bounds__(256, 3) void k_wprep(const float* __restrict__ W,
                                                  unsigned* __restrict__ Wb,    // [VPAD][384] uint pairs
                                                  float* __restrict__ inv_en) {
  __shared__ float ssb[32][8];   // per-row 8 partial sums of squares
  const int t = threadIdx.x;
  const int lane = t & 63, wave = t >> 6;
  const int v0 = blockIdx.x * 32;

  // bulk-issue all 24 loads (rows clamped to VOCAB-1: uniform, branch-free)
  float4 xv[8][3];
#pragma unroll
  for (int rr = 0; rr < 8; rr++) {
    const int v = v0 + wave * 8 + rr;
    const int vc = (v < VOCAB) ? v : (VOCAB - 1);
    const float* wrow = &W[(size_t)vc * HID + lane * 4];
#pragma unroll
    for (int c = 0; c < 3; c++)
      xv[rr][c] = *(const float4*)(wrow + c * 256);
  }
  __builtin_amdgcn_sched_barrier(0);   // pin: all loads issued before any store
#pragma unroll
  for (int rr = 0; rr < 8; rr++) {
    const int row = wave * 8 + rr;
    const int v = v0 + row;
    const bool valid = (v < VOCAB);
    unsigned* wbrow = &Wb[(size_t)v * (HID / 2) + lane * 2];
    float ss = 0.f;
#pragma unroll
    for (int c = 0; c < 3; c++) {
      float4 x = xv[rr][c];
      if (!valid) x = (float4){0.f, 0.f, 0.f, 0.f};
      *(uint2*)&wbrow[c * 128] = (uint2){pack2(x.x, x.y), pack2(x.z, x.w)};
      ss += x.x * x.x + x.y * x.y + x.z * x.z + x.w * x.w;
    }
    // 64 lane-partials -> 8 (xor 1,2,4 within 8-lane groups)
    ss += __shfl_xor(ss, 1, 64);
    ss += __shfl_xor(ss, 2, 64);
    ss += __shfl_xor(ss, 4, 64);
    if ((lane & 7) == 0) ssb[row][lane >> 3] = ss;
  }
  __syncthreads();
  // finish inv_en: 256 threads = 32 rows x 8 partials (identity map, no conflicts)
  {
    const int row = t >> 3, j = t & 7;
    float s = ssb[row][j];
    s += __shfl_xor(s, 1, 64);
    s += __shfl_xor(s, 2, 64);
    s += __shfl_xor(s, 4, 64);
    if (j == 0) {
      const int v = v0 + row;
      inv_en[v] = (v < VOCAB) ? (1.f / sqrtf(s)) : 0.f;
    }
  }
}

// obsb[b][i] = bf16(mean_c obs[b][c][i]), zero pad cols; packed uint stores
__global__ __launch_bounds__(256) void k_obs(const float* __restrict__ obs,
                                             unsigned* __restrict__ obsb) {
  int b = blockIdx.x, t = threadIdx.x;
  const size_t base = (size_t)b * 3 * IN;
  for (int p = t; p < NPAIR; p += 256) {
    float x = 0.f, y = 0.f;
    if (2 * p < IN) {   // IN even: pair never straddles the boundary
      float2 a0 = *(const float2*)&obs[base + 2 * p];
      float2 a1 = *(const float2*)&obs[base + IN + 2 * p];
      float2 a2 = *(const float2*)&obs[base + 2 * IN + 2 * p];
      x = (a0.x + a1.x + a2.x) * (1.f / 3.f);
      y = (a0.y + a1.y + a2.y) * (1.f / 3.f);
    }
    obsb[b * NPAIR + p] = pack2(x, y);
  }
}

__global__ __launch_bounds__(256) void k_proj(const float* __restrict__ proj,
                                              unsigned* __restrict__ projb) {
  int h = blockIdx.x, t = threadIdx.x;
  for (int p = t; p < NPAIR; p += 256) {
    float x = 0.f, y = 0.f;
    if (2 * p < IN) {
      float2 xy = *(const float2*)&proj[(size_t)h * IN + 2 * p];
      x = xy.x; y = xy.y;
    }
    projb[h * NPAIR + p] = pack2(x, y);
  }
}

// ---------------- q projection GEMM (K-split): qp[s] = partial obs @ proj^T ----

__global__ __launch_bounds__(256) void k_qgemm(const unsigned short* __restrict__ A,  // obsb [256][INPAD]
                                               const unsigned short* __restrict__ Bm, // projb [768][INPAD]
                                               float* __restrict__ qp) {              // [QSPLITS][256][768]
  __shared__ unsigned short As[64][32];
  __shared__ unsigned short Bs[64][32];
  const int t = threadIdx.x;
  const int lane = t & 63, wave = t >> 6;
  const int wm = wave >> 1, wn = wave & 1;
  const int quad = lane >> 4, lo = lane & 15;
  const int m0 = blockIdx.y * 64, n0 = blockIdx.x * 64;
  const int split = blockIdx.z;
  const int kbeg = split * QCHUNK, kend = kbeg + QCHUNK;
  const int ar = t >> 2, ac = (t & 3) * 8;
  f32x4 acc[2][2];
  for (int i = 0; i < 2; i++)
    for (int j = 0; j < 2; j++) acc[i][j] = (f32x4){0.f, 0.f, 0.f, 0.f};
  const unsigned short* aptr = &A[(m0 + ar) * INPAD + ac];
  const unsigned short* bptr = &Bm[(n0 + ar) * INPAD + ac];
  for (int k0 = kbeg; k0 < kend; k0 += 32) {
    uint4 av = *(const uint4*)(aptr + k0);
    uint4 bv = *(const uint4*)(bptr + k0);
    __syncthreads();
    *(uint4*)&As[ar][ac] = av;
    *(uint4*)&Bs[ar][ac] = bv;
    __syncthreads();
    bf16x8 af[2], bfr[2];
    for (int i = 0; i < 2; i++) {
      af[i]  = *(const bf16x8*)&As[wm * 32 + i * 16 + lo][quad * 8];
      bfr[i] = *(const bf16x8*)&Bs[wn * 32 + i * 16 + lo][quad * 8];
    }
    for (int mi = 0; mi < 2; mi++)
      for (int ni = 0; ni < 2; ni++)
        acc[mi][ni] = __builtin_amdgcn_mfma_f32_16x16x32_bf16(af[mi], bfr[ni], acc[mi][ni], 0, 0, 0);
  }
  float* outp = qp + (size_t)split * BATCH * HID;
  for (int mi = 0; mi < 2; mi++)
    for (int ni = 0; ni < 2; ni++)
      for (int r = 0; r < 4; r++) {
        int row = m0 + wm * 32 + mi * 16 + quad * 4 + r;   // b
        int col = n0 + wn * 32 + ni * 16 + lo;             // h
        outp[row * HID + col] = acc[mi][ni][r];            // 4B/lane, 16-lane contig
      }
}

// qhat[b][h] = bf16(sum_s qp * beta/||q_b||); packed uint stores; zero l
__global__ __launch_bounds__(384) void k_qhat(const float* __restrict__ qp,
                                              const int* __restrict__ beta,
                                              unsigned* __restrict__ qhat,
                                              float* __restrict__ l) {
  int b = blockIdx.x, t = threadIdx.x;   // 384 threads: pair t = cols 2t,2t+1
  float x = 0.f, y = 0.f;
  for (int s = 0; s < QSPLITS; s++) {
    float2 p = *(const float2*)&qp[(size_t)s * BATCH * HID + b * HID + 2 * t];
    x += p.x; y += p.y;
  }
  float ss = x * x + y * y;
  for (int m = 1; m < 64; m <<= 1) ss += __shfl_xor(ss, m, 64);
  __shared__ float sacc[6];
  if ((t & 63) == 0) sacc[t >> 6] = ss;
  __syncthreads();
  float tot = sacc[0] + sacc[1] + sacc[2] + sacc[3] + sacc[4] + sacc[5];
  // ref denom is (qn*en + 1e-8); qn*en ~ 1.3e3 so eps is rel ~7e-12: folded out.
  float scale = (float)beta[0] / sqrtf(tot);
  qhat[b * (HID / 2) + t] = pack2(x * scale, y * scale);
  if (t == 0) l[b] = 0.f;
}

// ---------------- GEMM1: E = exp((qhat @ Wb^T) * inv_en), rowsums into l ----
// grid (2 m-blocks, 393 n-blocks): adjacent blocks share the Wb stripe -> L2 hit.
// R9: reg-prefetch pipeline -- next k-step's loads issue after staging, hide
// under ds_read+MFMA+barrier.

__global__ __launch_bounds__(256) void k_gemm1(const unsigned short* __restrict__ A,   // qhat [256][768]
                                               const unsigned short* __restrict__ Bm,  // Wb [VPAD][768]
                                               const float* __restrict__ inv_en,
                                               unsigned short* __restrict__ E,         // [256][VPAD]
                                               float* __restrict__ l) {
  __shared__ unsigned short As[128][32];
  __shared__ unsigned short Bs[128][32];
  __shared__ unsigned short Et[128][128];   // staged output tile (32 KB)
  __shared__ float rowsum[128];
  const int t = threadIdx.x;
  const int lane = t & 63, wave = t >> 6;
  const int wm = wave >> 1, wn = wave & 1;
  const int quad = lane >> 4, lo = lane & 15;
  const int m0 = blockIdx.x * 128, n0 = blockIdx.y * 128;
  const int ar = t >> 2, ac = (t & 3) * 8;
  if (t < 128) rowsum[t] = 0.f;
  f32x4 acc[4][4];
  for (int i = 0; i < 4; i++)
    for (int j = 0; j < 4; j++) acc[i][j] = (f32x4){0.f, 0.f, 0.f, 0.f};
  const unsigned short* aptr  = &A[(m0 + ar) * HID + ac];
  const unsigned short* aptr2 = &A[(m0 + ar + 64) * HID + ac];
  const unsigned short* bptr  = &Bm[(size_t)(n0 + ar) * HID + ac];
  const unsigned short* bptr2 = &Bm[(size_t)(n0 + ar + 64) * HID + ac];
  // prologue: loads for k0=0
  uint4 av0 = *(const uint4*)(aptr);
  uint4 av1 = *(const uint4*)(aptr2);
  uint4 bv0 = *(const uint4*)(bptr);
  uint4 bv1 = *(const uint4*)(bptr2);
  for (int k0 = 0; k0 < HID; k0 += 32) {
    __syncthreads();
    *(uint4*)&As[ar][ac]      = av0;
    *(uint4*)&As[ar + 64][ac] = av1;
    *(uint4*)&Bs[ar][ac]      = bv0;
    *(uint4*)&Bs[ar + 64][ac] = bv1;
    __syncthreads();
    // prefetch next k-step (clamped dummy reload on last iter, discarded)
    const int kn = (k0 + 32 < HID) ? k0 + 32 : 0;
    av0 = *(const uint4*)(aptr + kn);
    av1 = *(const uint4*)(aptr2 + kn);
    bv0 = *(const uint4*)(bptr + kn);
    bv1 = *(const uint4*)(bptr2 + kn);
    __builtin_amdgcn_sched_barrier(0);   // loads issue before the MFMA cluster
    bf16x8 af[4], bfr[4];
    for (int i = 0; i < 4; i++) {
      af[i]  = *(const bf16x8*)&As[wm * 64 + i * 16 + lo][quad * 8];
      bfr[i] = *(const bf16x8*)&Bs[wn * 64 + i * 16 + lo][quad * 8];
    }
    for (int mi = 0; mi < 4; mi++)
      for (int ni = 0; ni < 4; ni++)
        acc[mi][ni] = __builtin_amdgcn_mfma_f32_16x16x32_bf16(af[mi], bfr[ni], acc[mi][ni], 0, 0, 0);
  }
  // epilogue: E = exp(acc * inv_en) into LDS tile + rowsum reduce
  for (int mi = 0; mi < 4; mi++)
    for (int ni = 0; ni < 4; ni++) {
      int cl = wn * 64 + ni * 16 + lo;
      int vg = n0 + cl;
      bool valid = (vg < VOCAB);
      float ie = inv_en[vg];
      for (int r = 0; r < 4; r++) {
        int row = wm * 64 + mi * 16 + quad * 4 + r;
        float e = valid ? __expf(acc[mi][ni][r] * ie) : 0.f;   // logits in [-8,8]
        Et[row][cl] = f2bf(e);
        float s = e;
        s += __shfl_xor(s, 1, 64);
        s += __shfl_xor(s, 2, 64);
        s += __shfl_xor(s, 4, 64);
        s += __shfl_xor(s, 8, 64);
        if (lo == 0) atomicAdd(&rowsum[row], s);
      }
    }
  __syncthreads();
  // cooperative full-line writes: 128 rows x 256B: 2048 uint4 = 8 passes x 256
  for (int i = 0; i < 8; i++) {
    int idx = t + i * 256;
    int row = idx >> 4, j = idx & 15;
    *(uint4*)&E[(size_t)(m0 + row) * VPAD + n0 + j * 8] = *(const uint4*)&Et[row][j * 8];
  }
  if (t < 128) atomicAdd(&l[m0 + t], rowsum[t]);
}

// ---------------- GEMM2 (K-split): Pp[s][h][b] = partial sum_v Wb[v][h]*E[b][v] ----
// R7 shape (3D grid, 128x128 tile) + R9 reg-prefetch pipeline.
// A-tile transposed during staging from row-major Wb: thread t reads Wb row
// v=t>>3, h-chunks (t&7),(t&7)+8 as uint4 (coalesced 128B/row/wave), writes 16
// transposed ds_write_u16 into As[128][34] (pitch 17 dwords: write banks
// ~4-way, hidden under MFMA; frag reads 4xb32 ~2-way).

__global__ __launch_bounds__(256) void k_gemm2(const unsigned short* __restrict__ Wb,  // [VPAD][768]
                                               const unsigned short* __restrict__ Bm,  // E [256][VPAD]
                                               float* __restrict__ Pp) {
  __shared__ unsigned short As[128][34];   // [m=h][k=v], padded pitch
  __shared__ unsigned short Bs[128][32];
  const int t = threadIdx.x;
  const int lane = t & 63, wave = t >> 6;
  const int wm = wave >> 1, wn = wave & 1;
  const int quad = lane >> 4, lo = lane & 15;
  const int m0 = blockIdx.x * 128, n0 = blockIdx.y * 128;   // m = h, n = b
  const int split = blockIdx.z;
  const int kbeg = split * CHUNK;
  const int kend = (kbeg + CHUNK < VPAD) ? kbeg + CHUNK : VPAD;
  const int sv = t >> 3, shc = t & 7;      // A-staging: Wb row sv, h-chunks shc/shc+8
  const int ar = t >> 2, ac = (t & 3) * 8; // B-staging
  f32x4 acc[4][4];
  for (int i = 0; i < 4; i++)
    for (int j = 0; j < 4; j++) acc[i][j] = (f32x4){0.f, 0.f, 0.f, 0.f};
  const unsigned short* bptr  = &Bm[(size_t)(n0 + ar) * VPAD + ac];
  const unsigned short* bptr2 = &Bm[(size_t)(n0 + ar + 64) * VPAD + ac];
  // prologue: loads for k0=kbeg
  uint4 a0  = *(const uint4*)&Wb[(size_t)(kbeg + sv) * HID + m0 + shc * 8];
  uint4 a1  = *(const uint4*)&Wb[(size_t)(kbeg + sv) * HID + m0 + (shc + 8) * 8];
  uint4 bv0 = *(const uint4*)(bptr + kbeg);
  uint4 bv1 = *(const uint4*)(bptr2 + kbeg);
  for (int k0 = kbeg; k0 < kend; k0 += 32) {
    __syncthreads();
    {
      const unsigned short* e0 = (const unsigned short*)&a0;
      const unsigned short* e1 = (const unsigned short*)&a1;
#pragma unroll
      for (int j = 0; j < 8; j++) {
        As[shc * 8 + j][sv]       = e0[j];   // coverage: m 0..63 x v 0..31
        As[(shc + 8) * 8 + j][sv] = e1[j];   // coverage: m 64..127 x v 0..31
      }
    }
    *(uint4*)&Bs[ar][ac]      = bv0;         // coverage: n 0..127 x k 0..31
    *(uint4*)&Bs[ar + 64][ac] = bv1;
    __syncthreads();
    // prefetch next k-step (clamped dummy reload on last iter, discarded)
    const int kn = (k0 + 32 < kend) ? k0 + 32 : kbeg;
    a0  = *(const uint4*)&Wb[(size_t)(kn + sv) * HID + m0 + shc * 8];
    a1  = *(const uint4*)&Wb[(size_t)(kn + sv) * HID + m0 + (shc + 8) * 8];
    bv0 = *(const uint4*)(bptr + kn);
    bv1 = *(const uint4*)(bptr2 + kn);
    __builtin_amdgcn_sched_barrier(0);   // loads issue before the MFMA cluster
    bf16x8 af[4], bfr[4];
#pragma unroll
    for (int i = 0; i < 4; i++) {
      const unsigned* rp = (const unsigned*)&As[wm * 64 + i * 16 + lo][quad * 8];
      uint4 u; u.x = rp[0]; u.y = rp[1]; u.z = rp[2]; u.w = rp[3];   // 4x b32
      af[i]  = *(const bf16x8*)&u;
      bfr[i] = *(const bf16x8*)&Bs[wn * 64 + i * 16 + lo][quad * 8];
    }
    for (int mi = 0; mi < 4; mi++)
      for (int ni = 0; ni < 4; ni++)
        acc[mi][ni] = __builtin_amdgcn_mfma_f32_16x16x32_bf16(af[mi], bfr[ni], acc[mi][ni], 0, 0, 0);
  }
  float* outp = Pp + (size_t)split * HID * BATCH;
  for (int mi = 0; mi < 4; mi++)
    for (int ni = 0; ni < 4; ni++)
      for (int r = 0; r < 4; r++) {
        int h = m0 + wm * 64 + mi * 16 + quad * 4 + r;
        int b = n0 + wn * 64 + ni * 16 + lo;
        outp[h * BATCH + b] = acc[mi][ni][r];   // 4B/lane, 16-lane contig
      }
}

// out[b][h] = (sum_s Pp[s][h][b]) / l[b]
__global__ __launch_bounds__(256) void k_reduce(const float* __restrict__ Pp,
                                                const float* __restrict__ l,
                                                float* __restrict__ out) {
  int idx = blockIdx.x * 256 + threadIdx.x;   // h*256 + b
  int h = idx >> 8, b = idx & 255;
  float s = 0.f;
  for (int i = 0; i < SPLITS; i++) s += Pp[(size_t)i * (HID * BATCH) + idx];
  out[b * HID + h] = s / l[b];
}

// ---------------- launch ----------------

extern "C" void kernel_launch(void* const* d_in, const int* in_sizes, int n_in,
                              void* d_out, int out_size, void* d_ws, size_t ws_size,
                              hipStream_t stream) {
  const float* obs  = (const float*)d_in[0];   // [256,3,84,84]
  const float* W    = (const float*)d_in[1];   // [50257,768]
  const float* proj = (const float*)d_in[2];   // [768,7056]
  const int* beta   = (const int*)d_in[3];     // scalar int
  float* out = (float*)d_out;                  // [256,768] f32

  char* ws = (char*)d_ws;
  size_t off = 0;
  auto alloc = [&](size_t bytes) -> void* {
    void* p = ws + off;
    off = (off + bytes + 255) & ~(size_t)255;
    return p;
  };
  unsigned short* Wb    = (unsigned short*)alloc((size_t)VPAD * HID * 2);   // 77.3 MB
  float* inv_en         = (float*)alloc((size_t)VPAD * 4);
  unsigned short* obsb  = (unsigned short*)alloc((size_t)BATCH * INPAD * 2);
  unsigned short* projb = (unsigned short*)alloc((size_t)HID * INPAD * 2);
  unsigned short* qhat  = (unsigned short*)alloc((size_t)BATCH * HID * 2);
  float* l              = (float*)alloc((size_t)BATCH * 4);
  unsigned short* E     = (unsigned short*)alloc((size_t)BATCH * VPAD * 2);  // 25.8 MB
  float* Pp             = (float*)alloc((size_t)SPLITS * BATCH * HID * 4);   // 25.2 MB
  float* qp             = Pp;   // alias: qp (13.4 MB) dead before gemm2 writes Pp
  (void)ws_size; (void)in_sizes; (void)n_in; (void)out_size;                 // ~129 MB total

  k_wprep<<<dim3(VPAD / 32), dim3(256), 0, stream>>>(W, (unsigned*)Wb, inv_en);
  k_obs  <<<dim3(BATCH), dim3(256), 0, stream>>>(obs, (unsigned*)obsb);
  k_proj <<<dim3(HID), dim3(256), 0, stream>>>(proj, (unsigned*)projb);
  k_qgemm<<<dim3(HID / 64, BATCH / 64, QSPLITS), dim3(256), 0, stream>>>(obsb, projb, qp);
  k_qhat <<<dim3(BATCH), dim3(384), 0, stream>>>(qp, beta, (unsigned*)qhat, l);
  k_gemm1<<<dim3(BATCH / 128, VPAD / 128), dim3(256), 0, stream>>>(qhat, Wb, inv_en, E, l);
  k_gemm2<<<dim3(HID / 128, BATCH / 128, SPLITS), dim3(256), 0, stream>>>(Wb, E, Pp);
  k_reduce<<<dim3(BATCH * HID / 256), dim3(256), 0, stream>>>(Pp, l, out);
}